// Round 9
// baseline (967.420 us; speedup 1.0000x reference)
//
#include <hip/hip_runtime.h>
#include <hip/hip_bf16.h>

// Geo2Vec fused MLP, bf16 MFMA. Round 9: R8 + explicit VGPR budget.
// Root cause of R7/R8 spill: hipcc caps 1024-thread kernels at 64 VGPR
// (targets 8 waves/EU) unless told otherwise. 16-wave block co-residency
// allows 128 VGPR; amdgpu_waves_per_eu(4,4) pins that budget.

typedef __attribute__((ext_vector_type(8))) __bf16 bfv8;
typedef __attribute__((ext_vector_type(8))) short s16x8;
typedef __attribute__((ext_vector_type(4))) float f32x4;
typedef __attribute__((ext_vector_type(4))) int i32x4;
typedef __attribute__((ext_vector_type(2))) int i32x2;

__device__ __forceinline__ short f2bf(float f) {
  unsigned u = __builtin_bit_cast(unsigned, f);
  u = (u + 0x7fffu + ((u >> 16) & 1u)) >> 16;
  return (short)u;
}
__device__ __forceinline__ float bf2f(short s) {
  unsigned u = ((unsigned)(unsigned short)s) << 16;
  return __builtin_bit_cast(float, u);
}
// Swizzle: conflict-free for 16-row A-reads and 4-row-group epilogue writes.
__device__ __forceinline__ int swzaddr(int base, int stride, int row, int colbyte) {
  return base + row * stride + (colbyte ^ (((row & 7) << 4) ^ ((row & 8) << 2)));
}
// LDS-visibility barrier that does NOT drain vmcnt (keeps B prefetch in flight).
__device__ __forceinline__ void ldsbar() {
  __builtin_amdgcn_sched_barrier(0);
  asm volatile("s_waitcnt lgkmcnt(0)");
  __builtin_amdgcn_s_barrier();
  __builtin_amdgcn_sched_barrier(0);
}

// ---------------- weight pack: fp32 row-major (K,256) -> bf16 B-frag-major ----
// packet p = (kt*16 + nt)*64 + lane ; dst[p*8+i] = W[kt*32 + 8*(lane>>4) + i][nt*16 + (lane&15)]
__global__ void pack_weights_kernel(const float* __restrict__ W1a, const float* __restrict__ W1b,
                                    const float* __restrict__ Wa, const float* __restrict__ Wb,
                                    short* __restrict__ ws) {
  int p = blockIdx.x * blockDim.x + threadIdx.x;
  const int P1 = 10240;           // W1a: 10 kt * 16 nt * 64
  const int P2 = P1 + 8192;       // W1b
  const int P3 = P2 + 8 * 18432;  // Wa
  const int P4 = P3 + 8 * 8192;   // Wb
  if (p >= P4) return;
  const float* src;
  int q;
  if (p < P1)      { src = W1a; q = p; }
  else if (p < P2) { src = W1b; q = p - P1; }
  else if (p < P3) { q = p - P2; int l = q / 18432; q -= l * 18432; src = Wa + l * 147456; }
  else             { q = p - P3; int l = q / 8192;  q -= l * 8192;  src = Wb + l * 65536; }
  const int lane = q & 63, t = q >> 6, nt = t & 15, kt = t >> 4;
  const int k0 = kt * 32 + ((lane >> 4) << 3);
  const int n  = (nt << 4) + (lane & 15);
  short* dst = ws + (size_t)p * 8;
#pragma unroll
  for (int i = 0; i < 8; ++i) dst[i] = f2bf(src[(size_t)(k0 + i) * 256 + n]);
}

// ---------------- fused MLP ----------------
// LDS (bytes): xyz [0,40960) stride 640 ; x [40960,73728) stride 512 ;
//              t [73728,106496) stride 512 ; f32 stage [106496,139264)
#define STG_BASE 106496

struct BPre { bfv8 b[2]; };
struct AFrag { bfv8 r0, r1, r2, r3; };

__device__ __forceinline__ bfv8 bfrag(const short* __restrict__ wp, int kt, int nt, int lane) {
  return *(const bfv8*)(wp + (((size_t)(kt * 16 + nt) * 64 + lane) << 3));
}

template<int SPLITKT>
__device__ __forceinline__ AFrag aload(const short* lds,
    int a1Base, int a1S, int a2Base, int a2S, int kt, int lo, int hi)
{
  const int base  = (kt < SPLITKT) ? a1Base : a2Base;
  const int strd  = (kt < SPLITKT) ? a1S : a2S;
  const int kk    = (kt < SPLITKT) ? kt : kt - SPLITKT;
  const int kbyte = kk * 64 + (hi << 4);
  AFrag f;
  f.r0 = *(const bfv8*)((const char*)lds + swzaddr(base, strd,       lo, kbyte));
  f.r1 = *(const bfv8*)((const char*)lds + swzaddr(base, strd, 16 + lo, kbyte));
  f.r2 = *(const bfv8*)((const char*)lds + swzaddr(base, strd, 32 + lo, kbyte));
  f.r3 = *(const bfv8*)((const char*)lds + swzaddr(base, strd, 48 + lo, kbyte));
  return f;
}

// Compute half of a GEMM's kt range [KT0,KT1), acc over 64 rows x 32 cols.
template<int KT0, int KT1, int SPLITKT>
__device__ __forceinline__ void ghalf(const short* lds,
    int a1Base, int a1S, int a2Base, int a2S,
    const short* __restrict__ wp, int wc, int lane,
    f32x4 (&acc)[4][2], BPre pre)
{
  constexpr int H = KT1 - KT0;
  const int lo = lane & 15, hi = lane >> 4;
  const int ntb = wc << 1;

  bfv8 bst[3][2];
  bst[0][0] = pre.b[0]; bst[0][1] = pre.b[1];
  if (H > 1) {
    bst[1][0] = bfrag(wp, KT0 + 1, ntb, lane);
    bst[1][1] = bfrag(wp, KT0 + 1, ntb + 1, lane);
  }
  AFrag ac = aload<SPLITKT>(lds, a1Base, a1S, a2Base, a2S, KT0, lo, hi);

#pragma unroll
  for (int i = 0; i < H; ++i) {
    const int kt = KT0 + i;
    if (i + 2 < H) {
      bst[(i + 2) % 3][0] = bfrag(wp, kt + 2, ntb, lane);
      bst[(i + 2) % 3][1] = bfrag(wp, kt + 2, ntb + 1, lane);
    }
    AFrag an;
    if (i + 1 < H) an = aload<SPLITKT>(lds, a1Base, a1S, a2Base, a2S, kt + 1, lo, hi);
    __builtin_amdgcn_s_setprio(1);
    acc[0][0] = __builtin_amdgcn_mfma_f32_16x16x32_bf16(ac.r0, bst[i % 3][0], acc[0][0], 0, 0, 0);
    acc[0][1] = __builtin_amdgcn_mfma_f32_16x16x32_bf16(ac.r0, bst[i % 3][1], acc[0][1], 0, 0, 0);
    acc[1][0] = __builtin_amdgcn_mfma_f32_16x16x32_bf16(ac.r1, bst[i % 3][0], acc[1][0], 0, 0, 0);
    acc[1][1] = __builtin_amdgcn_mfma_f32_16x16x32_bf16(ac.r1, bst[i % 3][1], acc[1][1], 0, 0, 0);
    acc[2][0] = __builtin_amdgcn_mfma_f32_16x16x32_bf16(ac.r2, bst[i % 3][0], acc[2][0], 0, 0, 0);
    acc[2][1] = __builtin_amdgcn_mfma_f32_16x16x32_bf16(ac.r2, bst[i % 3][1], acc[2][1], 0, 0, 0);
    acc[3][0] = __builtin_amdgcn_mfma_f32_16x16x32_bf16(ac.r3, bst[i % 3][0], acc[3][0], 0, 0, 0);
    acc[3][1] = __builtin_amdgcn_mfma_f32_16x16x32_bf16(ac.r3, bst[i % 3][1], acc[3][1], 0, 0, 0);
    __builtin_amdgcn_s_setprio(0);
    if (i + 1 < H) ac = an;  // struct copy = register moves
  }
}

template<int NKT, int SPLITKT, bool LEAKY>
__device__ __forceinline__ BPre do_gemm(short* lds,
    int a1Base, int a1S, int a2Base, int a2S,
    const short* __restrict__ wp, const short* __restrict__ wpn, int nxh,
    const float* __restrict__ bias, int outBase,
    int s, int wc, int lane, BPre pre)
{
  const int lo = lane & 15, hi = lane >> 4;
  f32x4 acc[4][2];
#pragma unroll
  for (int r = 0; r < 4; ++r) { acc[r][0] = (f32x4)0.f; acc[r][1] = (f32x4)0.f; }

  if (s == 0) ghalf<0, NKT / 2, SPLITKT>(lds, a1Base, a1S, a2Base, a2S, wp, wc, lane, acc, pre);
  else        ghalf<NKT / 2, NKT, SPLITKT>(lds, a1Base, a1S, a2Base, a2S, wp, wc, lane, acc, pre);

  // prefetch next gemm's first B frags for this wave's half (covered by epilogue)
  BPre nxt;
  nxt.b[0] = bfrag(wpn, s * nxh, (wc << 1), lane);
  nxt.b[1] = bfrag(wpn, s * nxh, (wc << 1) + 1, lane);

  const float bv0 = bias[(wc << 5) + lo];
  const float bv1 = bias[(wc << 5) + 16 + lo];
  char* stg = (char*)lds + STG_BASE;
  const int slot = ((wc << 6) + lane) << 4;  // per-(wc,lane) 16B granule, 4 planes of 8KB

#pragma unroll
  for (int p = 0; p < 2; ++p) {
    if (s) {  // dump partials: 4 x ds_write_b128, fully coalesced
      *(f32x4*)(stg + slot)         = acc[2 * p][0];
      *(f32x4*)(stg + 8192 + slot)  = acc[2 * p][1];
      *(f32x4*)(stg + 16384 + slot) = acc[2 * p + 1][0];
      *(f32x4*)(stg + 24576 + slot) = acc[2 * p + 1][1];
    }
    ldsbar();
    if (!s) {
      acc[2 * p][0]     += *(const f32x4*)(stg + slot);
      acc[2 * p][1]     += *(const f32x4*)(stg + 8192 + slot);
      acc[2 * p + 1][0] += *(const f32x4*)(stg + 16384 + slot);
      acc[2 * p + 1][1] += *(const f32x4*)(stg + 24576 + slot);
#pragma unroll
      for (int rq = 0; rq < 2; ++rq) {
        const int rt = 2 * p + rq;
#pragma unroll
        for (int ct = 0; ct < 2; ++ct)
#pragma unroll
          for (int rr = 0; rr < 4; ++rr) {
            const int orow = (rt << 4) + (hi << 2) + rr;
            const int col  = (wc << 5) + (ct << 4) + lo;
            float v = acc[rt][ct][rr] + (ct ? bv1 : bv0);
            if (LEAKY) v = (v >= 0.f) ? v : 0.01f * v;
            *(short*)((char*)lds + swzaddr(outBase, 512, orow, col << 1)) = f2bf(v);
          }
      }
    }
    ldsbar();  // protects stage-slot reuse (p=0) / out-region turnover (p=1)
  }
  return nxt;
}

__attribute__((amdgpu_flat_work_group_size(1024, 1024)))
__attribute__((amdgpu_waves_per_eu(4, 4)))
__global__ void geo2vec_kernel(const float* __restrict__ xy, const int* __restrict__ idx,
    const float* __restrict__ emb,
    const float* __restrict__ b1a, const float* __restrict__ b1b,
    const float* __restrict__ ba, const float* __restrict__ bb,
    const float* __restrict__ W2, const float* __restrict__ b2,
    const short* __restrict__ wp, float* __restrict__ out)
{
  __shared__ short lds[69632];  // 136 KB
  const int tid = threadIdx.x;
  const int wave = tid >> 6, lane = tid & 63;
  const int s = wave >> 3, wc = wave & 7;

  // issue first gemm's B stage-0 loads immediately: hide under prologue trig
  BPre pre;
  pre.b[0] = bfrag(wp, s * 5, (wc << 1), lane);
  pre.b[1] = bfrag(wp, s * 5, (wc << 1) + 1, lane);

  // ---- prologue: pos-encode + gather z -> xyz tile (64 x 320 bf16) ----
  {
    const int g = tid >> 4, j = tid & 15;  // 16 threads per row
    const int row = blockIdx.x * 64 + g;
    const float xv = xy[2 * row], yv = xy[2 * row + 1];
    const float rv = sqrtf(xv * xv + yv * yv);
    union { short sh[4]; i32x2 v; } tmp;
#pragma unroll
    for (int i = 0; i < 4; ++i) {
      const int c = 4 * j + i;
      float fv;
      if (c < 2)       fv = c ? yv : xv;
      else if (c < 22) { int m = c - 2;  float f = 1.0f + (5.0f / 9.0f) * (m >> 1); fv = sinf(((m & 1) ? yv : xv) * f); }
      else if (c < 42) { int m = c - 22; float f = 1.0f + (5.0f / 9.0f) * (m >> 1); fv = cosf(((m & 1) ? yv : xv) * f); }
      else if (c < 44) fv = (c == 42) ? xv : yv;
      else if (c < 54) fv = sinf(rv * (1.0f + (5.0f / 9.0f) * (c - 44)));
      else             fv = cosf(rv * (1.0f + (5.0f / 9.0f) * (c - 54)));
      tmp.sh[i] = f2bf(fv);
    }
    *(i32x2*)((char*)lds + swzaddr(0, 640, g, j << 3)) = tmp.v;
    const float* zr = emb + (size_t)(unsigned)idx[row] * 256;
#pragma unroll
    for (int c8 = 0; c8 < 2; ++c8) {
      const int cel = j * 16 + c8 * 8;
      const float4 f0 = *(const float4*)(zr + cel);
      const float4 f1 = *(const float4*)(zr + cel + 4);
      union { short sh[8]; i32x4 v; } t2;
      t2.sh[0] = f2bf(f0.x); t2.sh[1] = f2bf(f0.y); t2.sh[2] = f2bf(f0.z); t2.sh[3] = f2bf(f0.w);
      t2.sh[4] = f2bf(f1.x); t2.sh[5] = f2bf(f1.y); t2.sh[6] = f2bf(f1.z); t2.sh[7] = f2bf(f1.w);
      *(i32x4*)((char*)lds + swzaddr(0, 640, g, (64 + cel) << 1)) = t2.v;
    }
  }
  ldsbar();

  // layer 1
  pre = do_gemm<10, 10, true >(lds, 0, 640, 0, 640,         wp,         wp + 81920,  4, b1a, 73728, s, wc, lane, pre);
  pre = do_gemm<8,  8,  false>(lds, 73728, 512, 73728, 512, wp + 81920, wp + 147456, 9, b1b, 40960, s, wc, lane, pre);
  // 8 mid layers
  for (int l = 0; l < 8; ++l) {
    const short* wa = wp + 147456 + l * 147456;
    const short* wb = wp + 1327104 + l * 65536;
    const short* wan = (l < 7) ? (wa + 147456) : wp;  // dummy (valid mem) on last layer
    pre = do_gemm<18, 10, true >(lds, 0, 640, 40960, 512,     wa, wb,  4, ba + l * 256, 73728, s, wc, lane, pre);
    pre = do_gemm<8,  8,  false>(lds, 73728, 512, 73728, 512, wb, wan, 9, bb + l * 256, 40960, s, wc, lane, pre);
  }
  // final: out = x @ W2 + b2 ; 16 threads per row, width-16 shuffle reduce
  {
    const int r = tid >> 4, j = tid & 15;
    float sum = 0.f;
#pragma unroll
    for (int h = 0; h < 2; ++h) {
      const int cb = 32 * j + 16 * h;
      const s16x8 v = *(const s16x8*)((const char*)lds + swzaddr(40960, 512, r, cb));
      const int c0 = 16 * j + 8 * h;
      const float4 w0 = *(const float4*)(W2 + c0);
      const float4 w1 = *(const float4*)(W2 + c0 + 4);
      sum += bf2f(v[0]) * w0.x + bf2f(v[1]) * w0.y + bf2f(v[2]) * w0.z + bf2f(v[3]) * w0.w;
      sum += bf2f(v[4]) * w1.x + bf2f(v[5]) * w1.y + bf2f(v[6]) * w1.z + bf2f(v[7]) * w1.w;
    }
    sum += __shfl_xor(sum, 1); sum += __shfl_xor(sum, 2);
    sum += __shfl_xor(sum, 4); sum += __shfl_xor(sum, 8);
    if (j == 0) out[blockIdx.x * 64 + r] = sum + b2[0];
  }
}

extern "C" void kernel_launch(void* const* d_in, const int* in_sizes, int n_in,
                              void* d_out, int out_size, void* d_ws, size_t ws_size,
                              hipStream_t stream) {
  const float* xy  = (const float*)d_in[0];
  const int*   idx = (const int*)d_in[1];
  const float* emb = (const float*)d_in[2];
  const float* W1a = (const float*)d_in[3];
  const float* b1a = (const float*)d_in[4];
  const float* W1b = (const float*)d_in[5];
  const float* b1b = (const float*)d_in[6];
  const float* Wa  = (const float*)d_in[7];
  const float* ba  = (const float*)d_in[8];
  const float* Wb  = (const float*)d_in[9];
  const float* bb  = (const float*)d_in[10];
  const float* W2  = (const float*)d_in[11];
  const float* b2  = (const float*)d_in[12];
  short* ws = (short*)d_ws;
  const int B = in_sizes[1];

  hipLaunchKernelGGL(pack_weights_kernel, dim3(904), dim3(256), 0, stream,
                     W1a, W1b, Wa, Wb, ws);
  hipLaunchKernelGGL(geo2vec_kernel, dim3(B / 64), dim3(1024), 0, stream,
                     xy, idx, emb, b1a, b1b, ba, bb, W2, b2, ws, (float*)d_out);
}

// Round 10
// 646.157 us; speedup vs baseline: 1.4972x; 1.4972x over previous
//
#include <hip/hip_runtime.h>
#include <hip/hip_bf16.h>

// Geo2Vec fused MLP, bf16 MFMA. Round 10: R5 wave layout (16 waves, 32x32
// tiles, acc=16 regs) + 2-deep A and 2-deep B register pipelines sized to fit
// the 64-VGPR cap hipcc imposes on 1024-thread kernels (R7-R9 lesson: the cap
// cannot be lifted from source; pipeline must fit inside it).

typedef __attribute__((ext_vector_type(8))) __bf16 bfv8;
typedef __attribute__((ext_vector_type(8))) short s16x8;
typedef __attribute__((ext_vector_type(4))) float f32x4;
typedef __attribute__((ext_vector_type(4))) int i32x4;
typedef __attribute__((ext_vector_type(2))) int i32x2;

__device__ __forceinline__ short f2bf(float f) {
  unsigned u = __builtin_bit_cast(unsigned, f);
  u = (u + 0x7fffu + ((u >> 16) & 1u)) >> 16;
  return (short)u;
}
__device__ __forceinline__ float bf2f(short s) {
  unsigned u = ((unsigned)(unsigned short)s) << 16;
  return __builtin_bit_cast(float, u);
}
// Swizzle: conflict-free for 16-row A-reads and 4-row-group epilogue writes.
__device__ __forceinline__ int swzaddr(int base, int stride, int row, int colbyte) {
  return base + row * stride + (colbyte ^ (((row & 7) << 4) ^ ((row & 8) << 2)));
}
// LDS-visibility barrier that does NOT drain vmcnt (keeps B prefetch in flight).
__device__ __forceinline__ void ldsbar() {
  __builtin_amdgcn_sched_barrier(0);
  asm volatile("s_waitcnt lgkmcnt(0)");
  __builtin_amdgcn_s_barrier();
  __builtin_amdgcn_sched_barrier(0);
}

// ---------------- weight pack: fp32 row-major (K,256) -> bf16 B-frag-major ----
// packet p = (kt*16 + nt)*64 + lane ; dst[p*8+i] = W[kt*32 + 8*(lane>>4) + i][nt*16 + (lane&15)]
__global__ void pack_weights_kernel(const float* __restrict__ W1a, const float* __restrict__ W1b,
                                    const float* __restrict__ Wa, const float* __restrict__ Wb,
                                    short* __restrict__ ws) {
  int p = blockIdx.x * blockDim.x + threadIdx.x;
  const int P1 = 10240;           // W1a: 10 kt * 16 nt * 64
  const int P2 = P1 + 8192;       // W1b
  const int P3 = P2 + 8 * 18432;  // Wa
  const int P4 = P3 + 8 * 8192;   // Wb
  if (p >= P4) return;
  const float* src;
  int q;
  if (p < P1)      { src = W1a; q = p; }
  else if (p < P2) { src = W1b; q = p - P1; }
  else if (p < P3) { q = p - P2; int l = q / 18432; q -= l * 18432; src = Wa + l * 147456; }
  else             { q = p - P3; int l = q / 8192;  q -= l * 8192;  src = Wb + l * 65536; }
  const int lane = q & 63, t = q >> 6, nt = t & 15, kt = t >> 4;
  const int k0 = kt * 32 + ((lane >> 4) << 3);
  const int n  = (nt << 4) + (lane & 15);
  short* dst = ws + (size_t)p * 8;
#pragma unroll
  for (int i = 0; i < 8; ++i) dst[i] = f2bf(src[(size_t)(k0 + i) * 256 + n]);
}

// ---------------- fused MLP ----------------
// LDS (bytes): xyz [0,40960) stride 640 ; x [40960,73728) stride 512 ;
//              t [73728,106496) stride 512
struct BPre { bfv8 b0, b1; };
struct AFrag { bfv8 r0, r1; };

__device__ __forceinline__ bfv8 bfrag(const short* __restrict__ wp, int kt, int nt, int lane) {
  return *(const bfv8*)(wp + (((size_t)(kt * 16 + nt) * 64 + lane) << 3));
}

template<int SPLITKT>
__device__ __forceinline__ AFrag aload(const short* lds,
    int a1Base, int a1S, int a2Base, int a2S, int kt, int wrb, int lo, int hi)
{
  const int base  = (kt < SPLITKT) ? a1Base : a2Base;
  const int strd  = (kt < SPLITKT) ? a1S : a2S;
  const int kk    = (kt < SPLITKT) ? kt : kt - SPLITKT;
  const int kbyte = kk * 64 + (hi << 4);
  AFrag f;
  f.r0 = *(const bfv8*)((const char*)lds + swzaddr(base, strd, wrb + lo, kbyte));
  f.r1 = *(const bfv8*)((const char*)lds + swzaddr(base, strd, wrb + 16 + lo, kbyte));
  return f;
}

template<int NKT, int SPLITKT, bool LEAKY>
__device__ __forceinline__ BPre do_gemm(short* lds,
    int a1Base, int a1S, int a2Base, int a2S,
    const short* __restrict__ wp, const short* __restrict__ wpn,
    const float* __restrict__ bias, int outBase,
    int wr, int wc, int lane, BPre pre)
{
  const int lo = lane & 15, hi = lane >> 4;
  const int ntb = wc << 1;   // 2 coltiles per wave
  const int wrb = wr << 5;   // 32 rows per wave
  const float bv0 = bias[(ntb << 4) + lo];
  const float bv1 = bias[(ntb << 4) + 16 + lo];
  f32x4 acc[2][2];
#pragma unroll
  for (int r = 0; r < 2; ++r) { acc[r][0] = (f32x4)0.f; acc[r][1] = (f32x4)0.f; }

  // 2-deep register pipelines: slot i&1 consumed at iter i, filled at iter i-1.
  bfv8 bst[2][2];
  AFrag ast[2];
  bst[0][0] = pre.b0; bst[0][1] = pre.b1;
  ast[0] = aload<SPLITKT>(lds, a1Base, a1S, a2Base, a2S, 0, wrb, lo, hi);
  BPre nxt;

#pragma unroll
  for (int i = 0; i < NKT; ++i) {
    if (i + 1 < NKT) {
      bst[(i + 1) & 1][0] = bfrag(wp, i + 1, ntb, lane);
      bst[(i + 1) & 1][1] = bfrag(wp, i + 1, ntb + 1, lane);
      ast[(i + 1) & 1] = aload<SPLITKT>(lds, a1Base, a1S, a2Base, a2S, i + 1, wrb, lo, hi);
    } else {  // last iter: start next gemm's first B frags (fly over epilogue+barrier)
      nxt.b0 = bfrag(wpn, 0, ntb, lane);
      nxt.b1 = bfrag(wpn, 0, ntb + 1, lane);
    }
    __builtin_amdgcn_s_setprio(1);
    acc[0][0] = __builtin_amdgcn_mfma_f32_16x16x32_bf16(ast[i & 1].r0, bst[i & 1][0], acc[0][0], 0, 0, 0);
    acc[0][1] = __builtin_amdgcn_mfma_f32_16x16x32_bf16(ast[i & 1].r0, bst[i & 1][1], acc[0][1], 0, 0, 0);
    acc[1][0] = __builtin_amdgcn_mfma_f32_16x16x32_bf16(ast[i & 1].r1, bst[i & 1][0], acc[1][0], 0, 0, 0);
    acc[1][1] = __builtin_amdgcn_mfma_f32_16x16x32_bf16(ast[i & 1].r1, bst[i & 1][1], acc[1][1], 0, 0, 0);
    __builtin_amdgcn_s_setprio(0);
  }
  // epilogue: bias + (leaky) + bf16 round -> LDS
#pragma unroll
  for (int rt = 0; rt < 2; ++rt)
#pragma unroll
    for (int ct = 0; ct < 2; ++ct)
#pragma unroll
      for (int rr = 0; rr < 4; ++rr) {
        const int orow = wrb + (rt << 4) + (hi << 2) + rr;
        const int col  = ((ntb + ct) << 4) + lo;
        float v = acc[rt][ct][rr] + (ct ? bv1 : bv0);
        if (LEAKY) v = (v >= 0.f) ? v : 0.01f * v;
        *(short*)((char*)lds + swzaddr(outBase, 512, orow, col << 1)) = f2bf(v);
      }
  return nxt;
}

__launch_bounds__(1024, 1)
__global__ void geo2vec_kernel(const float* __restrict__ xy, const int* __restrict__ idx,
    const float* __restrict__ emb,
    const float* __restrict__ b1a, const float* __restrict__ b1b,
    const float* __restrict__ ba, const float* __restrict__ bb,
    const float* __restrict__ W2, const float* __restrict__ b2,
    const short* __restrict__ wp, float* __restrict__ out)
{
  __shared__ short lds[53248];  // 104 KB
  const int tid = threadIdx.x;
  const int wave = tid >> 6, lane = tid & 63;
  const int wr = wave >> 3, wc = wave & 7;

  // issue first gemm's B stage-0 loads immediately: hide under prologue trig
  BPre pre;
  pre.b0 = bfrag(wp, 0, (wc << 1), lane);
  pre.b1 = bfrag(wp, 0, (wc << 1) + 1, lane);

  // ---- prologue: pos-encode + gather z -> xyz tile (64 x 320 bf16) ----
  {
    const int g = tid >> 4, j = tid & 15;  // 16 threads per row
    const int row = blockIdx.x * 64 + g;
    const float xv = xy[2 * row], yv = xy[2 * row + 1];
    const float rv = sqrtf(xv * xv + yv * yv);
    union { short sh[4]; i32x2 v; } tmp;
#pragma unroll
    for (int i = 0; i < 4; ++i) {
      const int c = 4 * j + i;
      float fv;
      if (c < 2)       fv = c ? yv : xv;
      else if (c < 22) { int m = c - 2;  float f = 1.0f + (5.0f / 9.0f) * (m >> 1); fv = sinf(((m & 1) ? yv : xv) * f); }
      else if (c < 42) { int m = c - 22; float f = 1.0f + (5.0f / 9.0f) * (m >> 1); fv = cosf(((m & 1) ? yv : xv) * f); }
      else if (c < 44) fv = (c == 42) ? xv : yv;
      else if (c < 54) fv = sinf(rv * (1.0f + (5.0f / 9.0f) * (c - 44)));
      else             fv = cosf(rv * (1.0f + (5.0f / 9.0f) * (c - 54)));
      tmp.sh[i] = f2bf(fv);
    }
    *(i32x2*)((char*)lds + swzaddr(0, 640, g, j << 3)) = tmp.v;
    const float* zr = emb + (size_t)(unsigned)idx[row] * 256;
#pragma unroll
    for (int c8 = 0; c8 < 2; ++c8) {
      const int cel = j * 16 + c8 * 8;
      const float4 f0 = *(const float4*)(zr + cel);
      const float4 f1 = *(const float4*)(zr + cel + 4);
      union { short sh[8]; i32x4 v; } t2;
      t2.sh[0] = f2bf(f0.x); t2.sh[1] = f2bf(f0.y); t2.sh[2] = f2bf(f0.z); t2.sh[3] = f2bf(f0.w);
      t2.sh[4] = f2bf(f1.x); t2.sh[5] = f2bf(f1.y); t2.sh[6] = f2bf(f1.z); t2.sh[7] = f2bf(f1.w);
      *(i32x4*)((char*)lds + swzaddr(0, 640, g, (64 + cel) << 1)) = t2.v;
    }
  }
  ldsbar();

  // layer 1
  pre = do_gemm<10, 10, true >(lds, 0, 640, 0, 640,         wp,         wp + 81920,  b1a, 73728, wr, wc, lane, pre);
  ldsbar();
  pre = do_gemm<8,  8,  false>(lds, 73728, 512, 73728, 512, wp + 81920, wp + 147456, b1b, 40960, wr, wc, lane, pre);
  ldsbar();
  // 8 mid layers
  for (int l = 0; l < 8; ++l) {
    const short* wa = wp + 147456 + l * 147456;
    const short* wb = wp + 1327104 + l * 65536;
    const short* wan = (l < 7) ? (wa + 147456) : wp;  // dummy (valid mem) on last layer
    pre = do_gemm<18, 10, true >(lds, 0, 640, 40960, 512,     wa, wb,  ba + l * 256, 73728, wr, wc, lane, pre);
    ldsbar();
    pre = do_gemm<8,  8,  false>(lds, 73728, 512, 73728, 512, wb, wan, bb + l * 256, 40960, wr, wc, lane, pre);
    ldsbar();
  }
  // final: out = x @ W2 + b2 ; 16 threads per row, width-16 shuffle reduce
  {
    const int r = tid >> 4, j = tid & 15;
    float sum = 0.f;
#pragma unroll
    for (int h = 0; h < 2; ++h) {
      const int cb = 32 * j + 16 * h;
      const s16x8 v = *(const s16x8*)((const char*)lds + swzaddr(40960, 512, r, cb));
      const int c0 = 16 * j + 8 * h;
      const float4 w0 = *(const float4*)(W2 + c0);
      const float4 w1 = *(const float4*)(W2 + c0 + 4);
      sum += bf2f(v[0]) * w0.x + bf2f(v[1]) * w0.y + bf2f(v[2]) * w0.z + bf2f(v[3]) * w0.w;
      sum += bf2f(v[4]) * w1.x + bf2f(v[5]) * w1.y + bf2f(v[6]) * w1.z + bf2f(v[7]) * w1.w;
    }
    sum += __shfl_xor(sum, 1); sum += __shfl_xor(sum, 2);
    sum += __shfl_xor(sum, 4); sum += __shfl_xor(sum, 8);
    if (j == 0) out[blockIdx.x * 64 + r] = sum + b2[0];
  }
}

extern "C" void kernel_launch(void* const* d_in, const int* in_sizes, int n_in,
                              void* d_out, int out_size, void* d_ws, size_t ws_size,
                              hipStream_t stream) {
  const float* xy  = (const float*)d_in[0];
  const int*   idx = (const int*)d_in[1];
  const float* emb = (const float*)d_in[2];
  const float* W1a = (const float*)d_in[3];
  const float* b1a = (const float*)d_in[4];
  const float* W1b = (const float*)d_in[5];
  const float* b1b = (const float*)d_in[6];
  const float* Wa  = (const float*)d_in[7];
  const float* ba  = (const float*)d_in[8];
  const float* Wb  = (const float*)d_in[9];
  const float* bb  = (const float*)d_in[10];
  const float* W2  = (const float*)d_in[11];
  const float* b2  = (const float*)d_in[12];
  short* ws = (short*)d_ws;
  const int B = in_sizes[1];

  hipLaunchKernelGGL(pack_weights_kernel, dim3(904), dim3(256), 0, stream,
                     W1a, W1b, Wa, Wb, ws);
  hipLaunchKernelGGL(geo2vec_kernel, dim3(B / 64), dim3(1024), 0, stream,
                     xy, idx, emb, b1a, b1b, ba, bb, W2, b2, ws, (float*)d_out);
}